// Round 1
// baseline (362.145 us; speedup 1.0000x reference)
//
#include <hip/hip_runtime.h>
#include <hip/hip_bf16.h>

// Problem: B=8, C=256, H=W=256, P=16 -> h=w=16, 256 patches + 1 global row.
// ws layout (floats):
//   w1t:  [0,      65536)   transposed w1 (c-major)
//   w2t:  [65536, 131072)   transposed w2
//   mix:  [131072, 657408)  (B*257*256) mix[b][n][c]
//   m2 :  [657408, 1183744) (B*257*256) second-layer activations
//   att:  [1183744, 1185792) (B*256) softmax attention
#define WS_W1T 0
#define WS_W2T 65536
#define WS_MIX 131072
#define WS_M2  657408
#define WS_ATT 1183744

// ---------------- K0: transpose both weight matrices ----------------
__global__ void k_transpose(const float* __restrict__ w1,
                            const float* __restrict__ w2,
                            float* __restrict__ w1t,
                            float* __restrict__ w2t) {
    int t = blockIdx.x * 256 + threadIdx.x;  // 0..131071
    int idx = t & 65535;
    int o = idx >> 8, c = idx & 255;
    if (t < 65536) w1t[c * 256 + o] = w1[idx];
    else           w2t[c * 256 + o] = w2[idx];
}

// ---------------- K1: per-plane patch means + global mean ----------------
// One block (256 thr) per (b,c) plane of 256x256 floats.
__global__ void k_patch_means(const float* __restrict__ x,
                              float* __restrict__ mix) {
    int plane = blockIdx.x;           // b*256 + c
    int b = plane >> 8, c = plane & 255;
    const float4* p = (const float4*)x + (size_t)plane * 16384;
    int t = threadIdx.x;
    int lane = t & 63, wid = t >> 6;  // wid = row offset 0..3
    int pcol = lane >> 2;             // patch column this lane feeds

    __shared__ float bins[16][17];
    bins[t >> 4][t & 15] = 0.f;
    __syncthreads();

    float acc = 0.f;
    #pragma unroll 4
    for (int it = 0; it < 64; ++it) {
        int row = it * 4 + wid;
        float4 v = p[row * 64 + lane];
        acc += v.x + v.y + v.z + v.w;
        if ((it & 3) == 3) {  // finished patch-row it>>2
            acc += __shfl_xor(acc, 1);
            acc += __shfl_xor(acc, 2);
            if ((lane & 3) == 0) atomicAdd(&bins[it >> 2][pcol], acc);
            acc = 0.f;
        }
    }
    __syncthreads();

    // thread t owns patch n=t
    float pm = bins[t >> 4][t & 15] * (1.0f / 256.0f);  // patch mean
    mix[((size_t)b * 257 + t) * 256 + c] = pm;

    // global mean = mean of patch means
    float s = pm;
    for (int off = 1; off < 64; off <<= 1) s += __shfl_xor(s, off);
    __shared__ float wsum[4];
    if (lane == 0) wsum[wid] = s;
    __syncthreads();
    if (t == 0) {
        float g = (wsum[0] + wsum[1] + wsum[2] + wsum[3]) * (1.0f / 256.0f);
        mix[((size_t)b * 257 + 256) * 256 + c] = g;
    }
}

// ---------------- K2a: fused 2-layer MLP, 4 rows per block ----------------
// rows are the flattened (B*257) mix rows; batch boundaries don't matter.
__global__ void k_mlp(const float* __restrict__ mix,
                      const float* __restrict__ w1t, const float* __restrict__ b1,
                      const float* __restrict__ w2t, const float* __restrict__ b2,
                      float* __restrict__ m2out) {
    int r0 = blockIdx.x * 4;  // 514 blocks * 4 = 2056 rows
    int o = threadIdx.x;

    __shared__ float in[4][256];
    __shared__ float mid[4][256];
    #pragma unroll
    for (int j = 0; j < 4; ++j) in[j][o] = mix[(size_t)(r0 + j) * 256 + o];
    __syncthreads();

    float acc[4];
    float bb = b1[o];
    #pragma unroll
    for (int j = 0; j < 4; ++j) acc[j] = bb;
    #pragma unroll 4
    for (int c = 0; c < 256; ++c) {
        float wv = w1t[c * 256 + o];
        #pragma unroll
        for (int j = 0; j < 4; ++j) acc[j] = fmaf(in[j][c], wv, acc[j]);
    }
    #pragma unroll
    for (int j = 0; j < 4; ++j) mid[j][o] = fmaxf(acc[j], 0.f);
    __syncthreads();

    float bb2 = b2[o];
    #pragma unroll
    for (int j = 0; j < 4; ++j) acc[j] = bb2;
    #pragma unroll 4
    for (int c = 0; c < 256; ++c) {
        float wv = w2t[c * 256 + o];
        #pragma unroll
        for (int j = 0; j < 4; ++j) acc[j] = fmaf(mid[j][c], wv, acc[j]);
    }
    #pragma unroll
    for (int j = 0; j < 4; ++j)
        m2out[(size_t)(r0 + j) * 256 + o] = fmaxf(acc[j], 0.f);
}

// ---------------- K2b: scores + softmax per batch ----------------
__global__ void k_softmax(const float* __restrict__ m2,
                          float* __restrict__ att) {
    int b = blockIdx.x;
    const float* base = m2 + (size_t)b * 257 * 256;
    int t = threadIdx.x, lane = t & 63, wid = t >> 6;

    __shared__ float gf2[256];
    gf2[t] = base[256 * 256 + t];
    __syncthreads();

    const float* rowp = base + (size_t)t * 256;
    float s = 0.f;
    #pragma unroll 4
    for (int c = 0; c < 256; ++c) s = fmaf(rowp[c], gf2[c], s);

    // block max
    float m = s;
    for (int off = 1; off < 64; off <<= 1) m = fmaxf(m, __shfl_xor(m, off));
    __shared__ float red[4];
    if (lane == 0) red[wid] = m;
    __syncthreads();
    m = fmaxf(fmaxf(red[0], red[1]), fmaxf(red[2], red[3]));

    float e = __expf(s - m);
    float sum = e;
    for (int off = 1; off < 64; off <<= 1) sum += __shfl_xor(sum, off);
    __shared__ float red2[4];
    __syncthreads();
    if (lane == 0) red2[wid] = sum;
    __syncthreads();
    sum = red2[0] + red2[1] + red2[2] + red2[3];

    att[b * 256 + t] = e / sum;
}

// ---------------- K3: out = x * (1 + att_up) ----------------
__global__ void k_apply(const float* __restrict__ x,
                        const float* __restrict__ att,
                        float* __restrict__ out) {
    size_t i = (size_t)blockIdx.x * 256 + threadIdx.x;  // float4 index
    const float4* xv = (const float4*)x;
    float4* ov = (float4*)out;
    int plane = (int)(i >> 14);       // b*256 + c
    int j = (int)(i & 16383);
    int row = j >> 6, col4 = j & 63;
    int patch = ((row >> 4) << 4) | (col4 >> 2);
    int b = plane >> 8;
    float a = 1.0f + att[(b << 8) + patch];
    float4 v = xv[i];
    v.x *= a; v.y *= a; v.z *= a; v.w *= a;
    ov[i] = v;
}

extern "C" void kernel_launch(void* const* d_in, const int* in_sizes, int n_in,
                              void* d_out, int out_size, void* d_ws, size_t ws_size,
                              hipStream_t stream) {
    const float* x  = (const float*)d_in[0];
    const float* w1 = (const float*)d_in[1];
    const float* b1 = (const float*)d_in[2];
    const float* w2 = (const float*)d_in[3];
    const float* b2 = (const float*)d_in[4];
    float* out = (float*)d_out;
    float* ws  = (float*)d_ws;

    float* w1t = ws + WS_W1T;
    float* w2t = ws + WS_W2T;
    float* mix = ws + WS_MIX;
    float* m2  = ws + WS_M2;
    float* att = ws + WS_ATT;

    // K0: transpose weights (512 blocks)
    k_transpose<<<512, 256, 0, stream>>>(w1, w2, w1t, w2t);
    // K1: patch + global means (one block per (b,c) plane)
    k_patch_means<<<8 * 256, 256, 0, stream>>>(x, mix);
    // K2a: MLP over all 8*257 rows, 4 rows per block
    k_mlp<<<(8 * 257) / 4, 256, 0, stream>>>(mix, w1t, b1, w2t, b2, m2);
    // K2b: scores + softmax
    k_softmax<<<8, 256, 0, stream>>>(m2, att);
    // K3: elementwise apply; 33,554,432 float4 elements
    k_apply<<<(8 * 256 * 256 * 256 / 4) / 256, 256, 0, stream>>>(x, att, out);
}

// Round 2
// 315.437 us; speedup vs baseline: 1.1481x; 1.1481x over previous
//
#include <hip/hip_runtime.h>
#include <hip/hip_bf16.h>

typedef float f32x4 __attribute__((ext_vector_type(4)));

// Problem: B=8, C=256, H=W=256, P=16 -> h=w=16, 256 patches + 1 global row.
// ws layout (floats):
//   w1t:  [0,      65536)   transposed w1 (c-major)
//   w2t:  [65536, 131072)   transposed w2
//   mix:  [131072, 657408)  (B*257*256) mix[b][n][c]
//   m2 :  [657408, 1183744) (B*257*256) second-layer activations
//   att:  [1183744, 1185792) (B*256) softmax attention
#define WS_W1T 0
#define WS_W2T 65536
#define WS_MIX 131072
#define WS_M2  657408
#define WS_ATT 1183744

// ---------------- K0: transpose both weight matrices ----------------
__global__ void k_transpose(const float* __restrict__ w1,
                            const float* __restrict__ w2,
                            float* __restrict__ w1t,
                            float* __restrict__ w2t) {
    int t = blockIdx.x * 256 + threadIdx.x;  // 0..131071
    int idx = t & 65535;
    int o = idx >> 8, c = idx & 255;
    if (t < 65536) w1t[c * 256 + o] = w1[idx];
    else           w2t[c * 256 + o] = w2[idx];
}

// ---------------- K1: per-plane patch means + global mean ----------------
// One block (256 thr) per (b,c) plane of 256x256 floats.
// Wave wid owns rows [64*wid, 64*wid+64) = patch-rows [4*wid, 4*wid+4).
// No atomics: each (patch-row, patch-col) bin written by exactly one lane.
__global__ void k_patch_means(const float* __restrict__ x,
                              float* __restrict__ mix) {
    int plane = blockIdx.x;           // b*256 + c
    int b = plane >> 8, c = plane & 255;
    const f32x4* p = (const f32x4*)x + (size_t)plane * 16384;
    int t = threadIdx.x;
    int lane = t & 63, wid = t >> 6;
    int pcol = lane >> 2;             // patch column this 4-lane group feeds

    __shared__ float bins[16][16];

    const f32x4* wp = p + (size_t)wid * 64 * 64 + lane;  // wave's first row
    for (int band = 0; band < 4; ++band) {
        float acc = 0.f;
        #pragma unroll
        for (int r = 0; r < 16; ++r) {
            f32x4 v = __builtin_nontemporal_load(wp + (band * 16 + r) * 64);
            acc += v.x + v.y + v.z + v.w;
        }
        acc += __shfl_xor(acc, 1);
        acc += __shfl_xor(acc, 2);
        if ((lane & 3) == 0) bins[wid * 4 + band][pcol] = acc;
    }
    __syncthreads();

    // thread t owns patch n = t
    float pm = bins[t >> 4][t & 15] * (1.0f / 256.0f);  // patch mean
    mix[((size_t)b * 257 + t) * 256 + c] = pm;

    // global mean = mean of patch means (equal-sized patches)
    float s = pm;
    for (int off = 1; off < 64; off <<= 1) s += __shfl_xor(s, off);
    __shared__ float wsum[4];
    if (lane == 0) wsum[wid] = s;
    __syncthreads();
    if (t == 0) {
        float g = (wsum[0] + wsum[1] + wsum[2] + wsum[3]) * (1.0f / 256.0f);
        mix[((size_t)b * 257 + 256) * 256 + c] = g;
    }
}

// ---------------- K2a: fused 2-layer MLP, 4 rows per block ----------------
__global__ void k_mlp(const float* __restrict__ mix,
                      const float* __restrict__ w1t, const float* __restrict__ b1,
                      const float* __restrict__ w2t, const float* __restrict__ b2,
                      float* __restrict__ m2out) {
    int r0 = blockIdx.x * 4;  // 514 blocks * 4 = 2056 rows
    int o = threadIdx.x;

    __shared__ float in[4][256];
    __shared__ float mid[4][256];
    #pragma unroll
    for (int j = 0; j < 4; ++j) in[j][o] = mix[(size_t)(r0 + j) * 256 + o];
    __syncthreads();

    float acc[4];
    float bb = b1[o];
    #pragma unroll
    for (int j = 0; j < 4; ++j) acc[j] = bb;
    #pragma unroll 4
    for (int c = 0; c < 256; ++c) {
        float wv = w1t[c * 256 + o];
        #pragma unroll
        for (int j = 0; j < 4; ++j) acc[j] = fmaf(in[j][c], wv, acc[j]);
    }
    #pragma unroll
    for (int j = 0; j < 4; ++j) mid[j][o] = fmaxf(acc[j], 0.f);
    __syncthreads();

    float bb2 = b2[o];
    #pragma unroll
    for (int j = 0; j < 4; ++j) acc[j] = bb2;
    #pragma unroll 4
    for (int c = 0; c < 256; ++c) {
        float wv = w2t[c * 256 + o];
        #pragma unroll
        for (int j = 0; j < 4; ++j) acc[j] = fmaf(mid[j][c], wv, acc[j]);
    }
    #pragma unroll
    for (int j = 0; j < 4; ++j)
        m2out[(size_t)(r0 + j) * 256 + o] = fmaxf(acc[j], 0.f);
}

// ---------------- K2b: scores + softmax per batch ----------------
// 1024 threads = 16 waves; each wave dots 16 rows (float4-coalesced),
// then threads 0..255 do the block softmax.
__global__ void k_softmax(const float* __restrict__ m2,
                          float* __restrict__ att) {
    int b = blockIdx.x;
    const float* base = m2 + (size_t)b * 257 * 256;
    int t = threadIdx.x;          // 0..1023
    int lane = t & 63, w = t >> 6;

    __shared__ float gf2[256];
    __shared__ float scores[256];
    if (t < 256) gf2[t] = base[65536 + t];
    __syncthreads();

    f32x4 gv = ((const f32x4*)gf2)[lane];
    for (int r = 0; r < 16; ++r) {
        int n = w * 16 + r;
        f32x4 v = ((const f32x4*)(base + (size_t)n * 256))[lane];
        float s = v.x * gv.x + v.y * gv.y + v.z * gv.z + v.w * gv.w;
        #pragma unroll
        for (int off = 1; off < 64; off <<= 1) s += __shfl_xor(s, off);
        if (lane == 0) scores[n] = s;
    }
    __syncthreads();

    float s = (t < 256) ? scores[t] : -1e30f;
    float m = s;
    #pragma unroll
    for (int off = 1; off < 64; off <<= 1) m = fmaxf(m, __shfl_xor(m, off));
    __shared__ float redm[16];
    if (lane == 0) redm[w] = m;
    __syncthreads();
    float M = fmaxf(fmaxf(redm[0], redm[1]), fmaxf(redm[2], redm[3]));

    float e = (t < 256) ? __expf(s - M) : 0.f;
    float sum = e;
    #pragma unroll
    for (int off = 1; off < 64; off <<= 1) sum += __shfl_xor(sum, off);
    __shared__ float reds[16];
    if (lane == 0) reds[w] = sum;
    __syncthreads();
    float S = reds[0] + reds[1] + reds[2] + reds[3];

    if (t < 256) att[b * 256 + t] = e / S;
}

// ---------------- K3: out = x * (1 + att_up) ----------------
// 4 float4 per thread, nontemporal (pure 512 MiB sweep, no reuse).
__global__ void k_apply(const float* __restrict__ x,
                        const float* __restrict__ att,
                        float* __restrict__ out) {
    const f32x4* xv = (const f32x4*)x;
    f32x4* ov = (f32x4*)out;
    size_t base = (size_t)blockIdx.x * 1024 + threadIdx.x;
    #pragma unroll
    for (int k = 0; k < 4; ++k) {
        size_t i = base + (size_t)k * 256;
        int plane = (int)(i >> 14);       // b*256 + c
        int j = (int)(i & 16383);
        int row = j >> 6, col4 = j & 63;
        int patch = ((row >> 4) << 4) | (col4 >> 2);
        int b = plane >> 8;
        float a = 1.0f + att[(b << 8) + patch];
        f32x4 v = __builtin_nontemporal_load(&xv[i]);
        v.x *= a; v.y *= a; v.z *= a; v.w *= a;
        __builtin_nontemporal_store(v, &ov[i]);
    }
}

extern "C" void kernel_launch(void* const* d_in, const int* in_sizes, int n_in,
                              void* d_out, int out_size, void* d_ws, size_t ws_size,
                              hipStream_t stream) {
    const float* x  = (const float*)d_in[0];
    const float* w1 = (const float*)d_in[1];
    const float* b1 = (const float*)d_in[2];
    const float* w2 = (const float*)d_in[3];
    const float* b2 = (const float*)d_in[4];
    float* out = (float*)d_out;
    float* ws  = (float*)d_ws;

    float* w1t = ws + WS_W1T;
    float* w2t = ws + WS_W2T;
    float* mix = ws + WS_MIX;
    float* m2  = ws + WS_M2;
    float* att = ws + WS_ATT;

    k_transpose<<<512, 256, 0, stream>>>(w1, w2, w1t, w2t);
    k_patch_means<<<8 * 256, 256, 0, stream>>>(x, mix);
    k_mlp<<<(8 * 257) / 4, 256, 0, stream>>>(mix, w1t, b1, w2t, b2, m2);
    k_softmax<<<8, 1024, 0, stream>>>(m2, att);
    // 33,554,432 float4 / (256 thr * 4 per thr) = 32768 blocks
    k_apply<<<32768, 256, 0, stream>>>(x, att, out);
}